// Round 1
// 590.372 us; speedup vs baseline: 1.2943x; 1.2943x over previous
//
#include <hip/hip_runtime.h>
#include <math.h>

#define TRIALS 4096
#define STEPS  8192
#define ORDER  3
#define GEN    (STEPS - ORDER)   // 8189 generated steps per trial
#define NCHUNK 32
#define CLEN   256               // output steps per chunk (NCHUNK*CLEN == STEPS)

#define TPB        128           // threads per block for pass A / C
#define TPB_TRIALS 4             // trials per block (TPB / NCHUNK)
#define TILE       32            // steps per LDS tile
#define NTILE      (CLEN / TILE) // 8

// XOR swizzle: spreads column accesses across banks; keeps col in [0,32)
#define COL(s, e) ((e) ^ ((s) & 15))

// ---------------- Pass A: zero-init chunk scan -> tail state v_c ----------------
// Block = 128 threads = 4 trials x 32 chunks. Per tile, cooperatively load
// 128 segments x 32 float2 (256B contiguous per 32-lane group) into LDS,
// then each thread consumes its own chunk's stream from LDS.
__global__ __launch_bounds__(TPB) void pass_scan(
    const float2* __restrict__ normals,       // (TRIALS, GEN, 2) fp32
    const float* __restrict__ alpha,          // (3,2)
    const float* __restrict__ sigma,          // (2,)
    const float* __restrict__ rho_p,          // (1,)
    const float* __restrict__ mu,             // (2,)
    float* __restrict__ ws_v)                 // (TRIALS, NCHUNK, 6)
{
    __shared__ float2 lds[TPB][TILE];         // 128 x 32 x 8B = 32 KiB

    const int lt     = threadIdx.x;
    const int trial0 = blockIdx.x * TPB_TRIALS;
    const int c      = lt & 31;               // this thread's chunk
    const int e      = lt & 31;               // loader element lane
    const int sb     = lt >> 5;               // loader segment base (0..3)

    float a00 = alpha[0], a01 = alpha[1];
    float a10 = alpha[2], a11 = alpha[3];
    float a20 = alpha[4], a21 = alpha[5];
    float r   = rho_p[0];
    float c00 = sigma[0];
    float c10 = r * sigma[1];
    float c11 = sqrtf(1.0f - r * r) * sigma[1];
    float m0  = mu[0], m1 = mu[1];

    float x1 = 0.f, x2 = 0.f, x3 = 0.f;
    float y1 = 0.f, y2 = 0.f, y3 = 0.f;

    for (int j = 0; j < NTILE; ++j) {
        // cooperative coalesced load: segment s = chunk stream slice
        #pragma unroll
        for (int rr = 0; rr < 32; ++rr) {
            int s  = sb + (rr << 2);          // 0..127, each exactly once
            int tt = s >> 5;                  // trial_local
            int cc = s & 31;                  // chunk
            int g  = cc * CLEN - ORDER + (j << 5) + e;
            g = g < 0 ? 0 : g;                // clamp (chunk 0, tile 0 only)
            lds[s][COL(s, e)] = normals[(size_t)(trial0 + tt) * GEN + g];
        }
        __syncthreads();

        int i0 = (j == 0 && c == 0) ? ORDER : 0;
        #pragma unroll 4
        for (int i = i0; i < TILE; ++i) {
            float2 u = lds[lt][COL(lt, i)];
            float w0 = fmaf(u.x, c00, m0);
            float w1 = fmaf(u.y, c11, fmaf(u.x, c10, m1));
            float nx = fmaf(a20, x1, fmaf(a10, x2, fmaf(a00, x3, w0)));
            x3 = x2; x2 = x1; x1 = nx;
            float ny = fmaf(a21, y1, fmaf(a11, y2, fmaf(a01, y3, w1)));
            y3 = y2; y2 = y1; y1 = ny;
        }
        __syncthreads();
    }

    int tid = (trial0 + (lt >> 5)) * NCHUNK + c;
    float* v = ws_v + (size_t)tid * 6;
    v[0] = x1; v[1] = x2; v[2] = x3;
    v[3] = y1; v[4] = y2; v[5] = y3;
}

// ---------------- Pass B: affine combine (in-place v -> incoming state) --------
__global__ __launch_bounds__(256) void pass_combine(
    const float* __restrict__ alpha,
    const float* __restrict__ xmu_p,
    const float* __restrict__ x0p,            // (TRIALS, 3, 2)
    float* __restrict__ ws)
{
    int tid   = blockIdx.x * 256 + threadIdx.x;   // 8192 = TRIALS*2
    if (tid >= TRIALS * 2) return;
    int trial = tid >> 1;
    int d     = tid & 1;

    float a0 = alpha[0 * 2 + d];   // coef of oldest lag
    float a1 = alpha[1 * 2 + d];
    float a2 = alpha[2 * 2 + d];   // coef of newest lag
    float xm = xmu_p[d];

    // initial lag window: carry[0]=oldest -> x3, carry[2]=newest -> x1
    float x1 = x0p[(trial * 3 + 2) * 2 + d] - xm;
    float x2 = x0p[(trial * 3 + 1) * 2 + d] - xm;
    float x3 = x0p[(trial * 3 + 0) * 2 + d] - xm;

    float* w = ws + (size_t)trial * (NCHUNK * 6) + d * 3;

    // chunk 0 runs CLEN-ORDER noisy steps: s_in[1] = A^(CLEN-3) * s0 + v_0
    float v0 = w[0], v1 = w[1], v2 = w[2];
    w[0] = x1; w[1] = x2; w[2] = x3;
    for (int i = 0; i < CLEN - ORDER; ++i) {
        float nx = fmaf(a2, x1, fmaf(a1, x2, a0 * x3));
        x3 = x2; x2 = x1; x1 = nx;
    }
    x1 += v0; x2 += v1; x3 += v2;

    // M = A^CLEN via basis-vector evolution
    float m00 = 1.f, m10 = 0.f, m20 = 0.f;
    float m01 = 0.f, m11 = 1.f, m21 = 0.f;
    float m02 = 0.f, m12 = 0.f, m22 = 1.f;
    for (int i = 0; i < CLEN; ++i) {
        float t0 = fmaf(a2, m00, fmaf(a1, m10, a0 * m20));
        float t1 = fmaf(a2, m01, fmaf(a1, m11, a0 * m21));
        float t2 = fmaf(a2, m02, fmaf(a1, m12, a0 * m22));
        m20 = m10; m10 = m00; m00 = t0;
        m21 = m11; m11 = m01; m01 = t1;
        m22 = m12; m12 = m02; m02 = t2;
    }

    for (int c = 1; c < NCHUNK; ++c) {
        float* wc = w + c * 6;
        float u0 = wc[0], u1 = wc[1], u2 = wc[2];
        wc[0] = x1; wc[1] = x2; wc[2] = x3;
        float nx1 = m00 * x1 + m01 * x2 + m02 * x3 + u0;
        float nx2 = m10 * x1 + m11 * x2 + m12 * x3 + u1;
        float nx3 = m20 * x1 + m21 * x2 + m22 * x3 + u2;
        x1 = nx1; x2 = nx2; x3 = nx3;
    }
}

// ---------------- Pass C: emit fp32 outputs, LDS-staged both directions --------
__global__ __launch_bounds__(TPB) void pass_emit(
    const float2* __restrict__ normals,
    const float* __restrict__ alpha,
    const float* __restrict__ xmu_p,
    const float* __restrict__ sigma,
    const float* __restrict__ rho_p,
    const float* __restrict__ mu,
    const float* __restrict__ x0p,
    const float* __restrict__ ws,
    float2* __restrict__ out2)                // (TRIALS, STEPS, 2) fp32
{
    __shared__ float2 lds[TPB][TILE];         // 32 KiB

    const int lt     = threadIdx.x;
    const int trial0 = blockIdx.x * TPB_TRIALS;
    const int c      = lt & 31;
    const int e      = lt & 31;
    const int sb     = lt >> 5;
    const int trial  = trial0 + (lt >> 5);

    float a00 = alpha[0], a01 = alpha[1];
    float a10 = alpha[2], a11 = alpha[3];
    float a20 = alpha[4], a21 = alpha[5];
    float r   = rho_p[0];
    float c00 = sigma[0];
    float c10 = r * sigma[1];
    float c11 = sqrtf(1.0f - r * r) * sigma[1];
    float m0  = mu[0], m1 = mu[1];
    float xm0 = xmu_p[0], xm1 = xmu_p[1];

    const float* st = ws + ((size_t)trial * NCHUNK + c) * 6;
    float x1 = st[0], x2 = st[1], x3 = st[2];
    float y1 = st[3], y2 = st[4], y3 = st[5];

    for (int j = 0; j < NTILE; ++j) {
        #pragma unroll
        for (int rr = 0; rr < 32; ++rr) {
            int s  = sb + (rr << 2);
            int tt = s >> 5;
            int cc = s & 31;
            int g  = cc * CLEN - ORDER + (j << 5) + e;
            g = g < 0 ? 0 : g;
            lds[s][COL(s, e)] = normals[(size_t)(trial0 + tt) * GEN + g];
        }
        __syncthreads();

        if (j == 0 && c == 0) {
            // first ORDER output rows: (x_0 - xmu) + xmu, reference arithmetic
            #pragma unroll
            for (int k = 0; k < ORDER; ++k) {
                float v0 = (x0p[(trial * 3 + k) * 2 + 0] - xm0) + xm0;
                float v1 = (x0p[(trial * 3 + k) * 2 + 1] - xm1) + xm1;
                lds[lt][COL(lt, k)] = make_float2(v0, v1);
            }
        }
        int i0 = (j == 0 && c == 0) ? ORDER : 0;
        #pragma unroll 4
        for (int i = i0; i < TILE; ++i) {
            float2 u = lds[lt][COL(lt, i)];
            float w0 = fmaf(u.x, c00, m0);
            float w1 = fmaf(u.y, c11, fmaf(u.x, c10, m1));
            float nx = fmaf(a20, x1, fmaf(a10, x2, fmaf(a00, x3, w0)));
            x3 = x2; x2 = x1; x1 = nx;
            float ny = fmaf(a21, y1, fmaf(a11, y2, fmaf(a01, y3, w1)));
            y3 = y2; y2 = y1; y1 = ny;
            lds[lt][COL(lt, i)] = make_float2(nx + xm0, ny + xm1);
        }
        __syncthreads();

        // cooperative coalesced store: out index = c*CLEN + j*32 + e
        #pragma unroll
        for (int rr = 0; rr < 32; ++rr) {
            int s  = sb + (rr << 2);
            int tt = s >> 5;
            int cc = s & 31;
            out2[(size_t)(trial0 + tt) * STEPS + cc * CLEN + (j << 5) + e] =
                lds[s][COL(s, e)];
        }
        __syncthreads();
    }
}

extern "C" void kernel_launch(void* const* d_in, const int* in_sizes, int n_in,
                              void* d_out, int out_size, void* d_ws, size_t ws_size,
                              hipStream_t stream) {
    const float*  alpha = (const float*)d_in[0];
    const float*  xmu   = (const float*)d_in[1];
    const float*  sigma = (const float*)d_in[2];
    const float*  rho   = (const float*)d_in[3];
    const float*  mu    = (const float*)d_in[4];
    const float*  x0    = (const float*)d_in[5];
    const float2* norm2 = (const float2*)d_in[6];
    float2*       out2  = (float2*)d_out;
    float*        ws    = (float*)d_ws;   // needs TRIALS*NCHUNK*6*4 = 3 MiB

    int blocksAC = TRIALS / TPB_TRIALS;          // 1024 blocks x 128 threads
    hipLaunchKernelGGL(pass_scan, dim3(blocksAC), dim3(TPB), 0, stream,
                       norm2, alpha, sigma, rho, mu, ws);

    int threadsB = TRIALS * 2;                   // 8192
    hipLaunchKernelGGL(pass_combine, dim3(threadsB / 256), dim3(256), 0, stream,
                       alpha, xmu, x0, ws);

    hipLaunchKernelGGL(pass_emit, dim3(blocksAC), dim3(TPB), 0, stream,
                       norm2, alpha, xmu, sigma, rho, mu, x0, ws, out2);
}

// Round 2
// 462.081 us; speedup vs baseline: 1.6537x; 1.2776x over previous
//
#include <hip/hip_runtime.h>
#include <math.h>

#define TRIALS 4096
#define STEPS  8192
#define ORDER  3
#define GEN    (STEPS - ORDER)   // 8189 generated steps per trial
#define NCHUNK 256               // chunks per trial (= threads per block)
#define CLEN   32                // steps per chunk
#define TPB    256
#define HTILE  16                // steps per LDS sub-tile
#define NSUB   (CLEN / HTILE)    // 2
#define KS_ROUNDS 8              // log2(NCHUNK)

// ---------------- Setup: W_r = A^(CLEN * 2^r), r=0..7, both dims -> ws --------
// Layout: ws[r*18 + d*9 + (i*3+j)] = W_r^{(d)}[i][j], z_new[i] = sum_j W[i][j] z[j]
__global__ void setup_powers(const float* __restrict__ alpha,
                             float* __restrict__ wsW)
{
    if (threadIdx.x != 0 || blockIdx.x != 0) return;
    for (int d = 0; d < 2; ++d) {
        float a0 = alpha[0 * 2 + d];   // oldest-lag coef
        float a1 = alpha[1 * 2 + d];
        float a2 = alpha[2 * 2 + d];   // newest-lag coef
        // basis evolution: W = A^CLEN
        float w00 = 1.f, w10 = 0.f, w20 = 0.f;
        float w01 = 0.f, w11 = 1.f, w21 = 0.f;
        float w02 = 0.f, w12 = 0.f, w22 = 1.f;
        for (int i = 0; i < CLEN; ++i) {
            float t0 = fmaf(a2, w00, fmaf(a1, w10, a0 * w20));
            float t1 = fmaf(a2, w01, fmaf(a1, w11, a0 * w21));
            float t2 = fmaf(a2, w02, fmaf(a1, w12, a0 * w22));
            w20 = w10; w10 = w00; w00 = t0;
            w21 = w11; w11 = w01; w01 = t1;
            w22 = w12; w12 = w02; w02 = t2;
        }
        for (int r = 0; r < KS_ROUNDS; ++r) {
            float* o = wsW + r * 18 + d * 9;
            o[0] = w00; o[1] = w01; o[2] = w02;
            o[3] = w10; o[4] = w11; o[5] = w12;
            o[6] = w20; o[7] = w21; o[8] = w22;
            if (r < KS_ROUNDS - 1) {   // W <- W*W
                float n00 = fmaf(w00, w00, fmaf(w01, w10, w02 * w20));
                float n01 = fmaf(w00, w01, fmaf(w01, w11, w02 * w21));
                float n02 = fmaf(w00, w02, fmaf(w01, w12, w02 * w22));
                float n10 = fmaf(w10, w00, fmaf(w11, w10, w12 * w20));
                float n11 = fmaf(w10, w01, fmaf(w11, w11, w12 * w21));
                float n12 = fmaf(w10, w02, fmaf(w11, w12, w12 * w22));
                float n20 = fmaf(w20, w00, fmaf(w21, w10, w22 * w20));
                float n21 = fmaf(w20, w01, fmaf(w21, w11, w22 * w21));
                float n22 = fmaf(w20, w02, fmaf(w21, w12, w22 * w22));
                w00 = n00; w01 = n01; w02 = n02;
                w10 = n10; w11 = n11; w12 = n12;
                w20 = n20; w21 = n21; w22 = n22;
            }
        }
    }
}

// ---------------- Fused: scan (zero-init, v in regs) + KS combine + emit ------
// One block = one trial. Noise read from HBM exactly once.
__global__ __launch_bounds__(TPB) void pass_fused(
    const float2* __restrict__ normals,       // (TRIALS, GEN, 2) fp32
    const float* __restrict__ alpha,
    const float* __restrict__ xmu_p,
    const float* __restrict__ sigma,
    const float* __restrict__ rho_p,
    const float* __restrict__ mu,
    const float* __restrict__ x0p,            // (TRIALS, 3, 2)
    const float* __restrict__ wsW,            // KS matrices from setup_powers
    float2* __restrict__ out2)                // (TRIALS, STEPS, 2)
{
    __shared__ float2 lds[NCHUNK][HTILE];     // 32 KiB; reused as KS state

    const int lt    = threadIdx.x;            // chunk index within trial
    const int trial = blockIdx.x;
    const int e     = lt & 15;                // loader element lane
    const int sb    = lt >> 4;                // loader segment sub-index (0..15)

    float a00 = alpha[0], a01 = alpha[1];
    float a10 = alpha[2], a11 = alpha[3];
    float a20 = alpha[4], a21 = alpha[5];
    float r   = rho_p[0];
    float c00 = sigma[0];
    float c10 = r * sigma[1];
    float c11 = sqrtf(1.0f - r * r) * sigma[1];
    float m0  = mu[0], m1 = mu[1];
    float xm0 = xmu_p[0], xm1 = xmu_p[1];

    const float2* np = normals + (size_t)trial * GEN;

    // ---- Phase 1: zero-init scan, per-step values held in registers ----
    float vx[CLEN], vy[CLEN];
    float x1 = 0.f, x2 = 0.f, x3 = 0.f;
    float y1 = 0.f, y2 = 0.f, y3 = 0.f;

    #pragma unroll
    for (int jj = 0; jj < NSUB; ++jj) {
        #pragma unroll
        for (int rr = 0; rr < 16; ++rr) {
            int s = rr * 16 + sb;                       // each row once
            int g = s * CLEN - ORDER + jj * HTILE + e;  // chunk s noise index
            g = g < 0 ? 0 : g;                          // clamp (chunk 0 only)
            lds[s][e ^ sb] = np[g];                     // s&15 == sb
        }
        __syncthreads();
        #pragma unroll
        for (int i = 0; i < HTILE; ++i) {
            int idx = jj * HTILE + i;
            if (!(lt == 0 && idx < ORDER)) {            // chunk 0: skip pads
                float2 u = lds[lt][i ^ (lt & 15)];
                float w0 = fmaf(u.x, c00, m0);
                float w1 = fmaf(u.y, c11, fmaf(u.x, c10, m1));
                float nx = fmaf(a20, x1, fmaf(a10, x2, fmaf(a00, x3, w0)));
                x3 = x2; x2 = x1; x1 = nx;
                float ny = fmaf(a21, y1, fmaf(a11, y2, fmaf(a01, y3, w1)));
                y3 = y2; y2 = y1; y1 = ny;
                vx[idx] = x1; vy[idx] = y1;
            }
        }
        __syncthreads();
    }

    // ---- Phase 2a: chunk 0 folds in the true initial state ----
    // t'_0 = A^(CLEN-3) * s0 + tail_0  (== s_in[1], matches old pass_combine)
    if (lt == 0) {
        float sx1 = x0p[(trial * 3 + 2) * 2 + 0] - xm0;
        float sx2 = x0p[(trial * 3 + 1) * 2 + 0] - xm0;
        float sx3 = x0p[(trial * 3 + 0) * 2 + 0] - xm0;
        float sy1 = x0p[(trial * 3 + 2) * 2 + 1] - xm1;
        float sy2 = x0p[(trial * 3 + 1) * 2 + 1] - xm1;
        float sy3 = x0p[(trial * 3 + 0) * 2 + 1] - xm1;
        for (int i = 0; i < CLEN - ORDER; ++i) {
            float nx = fmaf(a20, sx1, fmaf(a10, sx2, a00 * sx3));
            sx3 = sx2; sx2 = sx1; sx1 = nx;
            float ny = fmaf(a21, sy1, fmaf(a11, sy2, a01 * sy3));
            sy3 = sy2; sy2 = sy1; sy1 = ny;
        }
        x1 += sx1; x2 += sx2; x3 += sx3;
        y1 += sy1; y2 += sy2; y3 += sy3;
    }

    // ---- Phase 2b: Kogge-Stone affine scan across 256 chunks ----
    // z_c after 8 rounds = s_in[c+1]; matrices W_r = A^(32*2^r) from wsW.
    float* st = (float*)lds;                  // 256*7 floats, stride 7 (banks)
    float zx1 = x1, zx2 = x2, zx3 = x3;
    float zy1 = y1, zy2 = y2, zy3 = y3;
    #pragma unroll
    for (int rnd = 0; rnd < KS_ROUNDS; ++rnd) {
        int off = 1 << rnd;
        int b = lt * 7;
        st[b + 0] = zx1; st[b + 1] = zx2; st[b + 2] = zx3;
        st[b + 3] = zy1; st[b + 4] = zy2; st[b + 5] = zy3;
        __syncthreads();
        if (lt >= off) {
            const float* Wp = wsW + rnd * 18;
            float wx00 = Wp[0], wx01 = Wp[1], wx02 = Wp[2];
            float wx10 = Wp[3], wx11 = Wp[4], wx12 = Wp[5];
            float wx20 = Wp[6], wx21 = Wp[7], wx22 = Wp[8];
            float wy00 = Wp[9],  wy01 = Wp[10], wy02 = Wp[11];
            float wy10 = Wp[12], wy11 = Wp[13], wy12 = Wp[14];
            float wy20 = Wp[15], wy21 = Wp[16], wy22 = Wp[17];
            int pb = (lt - off) * 7;
            float p1 = st[pb + 0], p2 = st[pb + 1], p3 = st[pb + 2];
            float q1 = st[pb + 3], q2 = st[pb + 4], q3 = st[pb + 5];
            zx1 = fmaf(wx00, p1, fmaf(wx01, p2, fmaf(wx02, p3, zx1)));
            zx2 = fmaf(wx10, p1, fmaf(wx11, p2, fmaf(wx12, p3, zx2)));
            zx3 = fmaf(wx20, p1, fmaf(wx21, p2, fmaf(wx22, p3, zx3)));
            zy1 = fmaf(wy00, q1, fmaf(wy01, q2, fmaf(wy02, q3, zy1)));
            zy2 = fmaf(wy10, q1, fmaf(wy11, q2, fmaf(wy12, q3, zy2)));
            zy3 = fmaf(wy20, q1, fmaf(wy21, q2, fmaf(wy22, q3, zy3)));
        }
        __syncthreads();
    }

    // distribute: chunk c's incoming state = z_{c-1}; chunk 0 uses s0
    {
        int b = lt * 7;
        st[b + 0] = zx1; st[b + 1] = zx2; st[b + 2] = zx3;
        st[b + 3] = zy1; st[b + 4] = zy2; st[b + 5] = zy3;
    }
    __syncthreads();
    float cx1, cx2, cx3, cy1, cy2, cy3;
    if (lt == 0) {
        cx1 = x0p[(trial * 3 + 2) * 2 + 0] - xm0;
        cx2 = x0p[(trial * 3 + 1) * 2 + 0] - xm0;
        cx3 = x0p[(trial * 3 + 0) * 2 + 0] - xm0;
        cy1 = x0p[(trial * 3 + 2) * 2 + 1] - xm1;
        cy2 = x0p[(trial * 3 + 1) * 2 + 1] - xm1;
        cy3 = x0p[(trial * 3 + 0) * 2 + 1] - xm1;
    } else {
        int pb = (lt - 1) * 7;
        cx1 = st[pb + 0]; cx2 = st[pb + 1]; cx3 = st[pb + 2];
        cy1 = st[pb + 3]; cy2 = st[pb + 4]; cy3 = st[pb + 5];
    }
    __syncthreads();   // KS state reads done before emit overwrites lds

    // ---- Phase 3: emit out[k] = v[k] + (A^{k+1} s_in)[0] + xmu ----
    #pragma unroll
    for (int jj = 0; jj < NSUB; ++jj) {
        #pragma unroll
        for (int i = 0; i < HTILE; ++i) {
            int k = jj * HTILE + i;
            float o0, o1;
            if (lt == 0 && k < ORDER) {
                o0 = (x0p[(trial * 3 + k) * 2 + 0] - xm0) + xm0;
                o1 = (x0p[(trial * 3 + k) * 2 + 1] - xm1) + xm1;
            } else {
                float nx = fmaf(a20, cx1, fmaf(a10, cx2, a00 * cx3));
                cx3 = cx2; cx2 = cx1; cx1 = nx;
                float ny = fmaf(a21, cy1, fmaf(a11, cy2, a01 * cy3));
                cy3 = cy2; cy2 = cy1; cy1 = ny;
                o0 = (vx[k] + cx1) + xm0;
                o1 = (vy[k] + cy1) + xm1;
            }
            lds[lt][i ^ (lt & 15)] = make_float2(o0, o1);
        }
        __syncthreads();
        #pragma unroll
        for (int rr = 0; rr < 16; ++rr) {
            int s = rr * 16 + sb;
            out2[(size_t)trial * STEPS + s * CLEN + jj * HTILE + e] =
                lds[s][e ^ sb];
        }
        __syncthreads();
    }
}

extern "C" void kernel_launch(void* const* d_in, const int* in_sizes, int n_in,
                              void* d_out, int out_size, void* d_ws, size_t ws_size,
                              hipStream_t stream) {
    const float*  alpha = (const float*)d_in[0];
    const float*  xmu   = (const float*)d_in[1];
    const float*  sigma = (const float*)d_in[2];
    const float*  rho   = (const float*)d_in[3];
    const float*  mu    = (const float*)d_in[4];
    const float*  x0    = (const float*)d_in[5];
    const float2* norm2 = (const float2*)d_in[6];
    float2*       out2  = (float2*)d_out;
    float*        wsW   = (float*)d_ws;       // 144 floats used

    hipLaunchKernelGGL(setup_powers, dim3(1), dim3(64), 0, stream, alpha, wsW);
    hipLaunchKernelGGL(pass_fused, dim3(TRIALS), dim3(TPB), 0, stream,
                       norm2, alpha, xmu, sigma, rho, mu, x0, wsW, out2);
}